// Round 13
// baseline (230.197 us; speedup 1.0000x reference)
//
#include <hip/hip_runtime.h>

#define T_STEPS 16
#define H 64
#define S_IN 25
#define A_OUT 4
#define NB 65536
#define UPW 16            // units per thread (H / 4 waves)
#define EPB 64            // batch elements per block (one per lane)

typedef unsigned long long ull;

__device__ __forceinline__ float fmaf_(float a, float b, float c) { return __builtin_fmaf(a, b, c); }

// Transpose W2 (64x64) and W3 (4x64) into workspace (row-major [k][h], [h][a]).
__global__ void snn_prep(const float* __restrict__ W2, const float* __restrict__ W3,
                         float* __restrict__ W2T, float* __restrict__ W3T) {
    int i = blockIdx.x * blockDim.x + threadIdx.x;
    if (i < H * H) { int h = i >> 6, k = i & 63; W2T[k * H + h] = W2[h * H + k]; }
    if (i < A_OUT * H) { int a = i >> 6, h = i & 63; W3T[h * A_OUT + a] = W3[a * H + h]; }
}

// R5 shape (4 waves x UPW=16, lane = batch element) + LDS weight path with
// VGPR headroom: __launch_bounds__(256,4) -> 128-reg cap, so the compiler can
// keep ~4 iterations of broadcast ds_read_b128 in flight WITHOUT spilling
// (R11's failure mode: 64-reg cap -> cur1/m1 spilled to scratch, 72MB writes).
// R12 bug fixed: m3acc init must be a strided loop at 256 threads (was a
// tid<512 guard -> half of m3acc kept 0xAA poison -> NaN).
__global__ __launch_bounds__(256, 4) void snn_main(
    const float* __restrict__ x,
    const float* __restrict__ W1, const float* __restrict__ b1,
    const float* __restrict__ W2T, const float* __restrict__ b2,
    const float* __restrict__ W3T, const float* __restrict__ b3,
    float* __restrict__ out, int* __restrict__ g_pre, int* __restrict__ g_post)
{
#pragma clang fp contract(off)
    __shared__ float w2s[H][H];                 // 16 KB: W2T rows, broadcast-read
    __shared__ float4 w3s[H];                   // 1 KB: W3T rows
    __shared__ unsigned int s1buf[2][4][EPB];   // [slot][wave][elem] 16-bit quarter masks
    __shared__ unsigned int s2buf[2][4][EPB];
    __shared__ float m3acc[EPB][8];             // [elem][0..3]=m3, [4..7]=acc
    __shared__ int lds_pre[T_STEPS * H];
    __shared__ int lds_post[T_STEPS * A_OUT];

    const int tid = threadIdx.x;
    for (int i = tid; i < (H * H) / 4; i += 256)
        reinterpret_cast<float4*>(&w2s[0][0])[i] = reinterpret_cast<const float4*>(W2T)[i];
    if (tid < H) w3s[tid] = reinterpret_cast<const float4*>(W3T)[tid];
    for (int i = tid; i < T_STEPS * H; i += 256) lds_pre[i] = 0;
    if (tid < T_STEPS * A_OUT) lds_post[tid] = 0;
    for (int i = tid; i < EPB * 8; i += 256) (&m3acc[0][0])[i] = 0.0f;   // FIXED

    const int lane  = tid & 63;
    const int wq    = __builtin_amdgcn_readfirstlane(tid >> 6);  // wave id 0..3 (SGPR)
    const int hbase = UPW * wq;                                  // this wave's unit range
    const int b     = blockIdx.x * EPB + lane;                   // batch element

    // cur1 for this thread's 16 units (same s-chain as reference)
    float cur1[UPW];
    {
        float xv[S_IN];
        #pragma unroll
        for (int s = 0; s < S_IN; ++s) xv[s] = x[b * S_IN + s];
        #pragma unroll
        for (int j = 0; j < UPW; ++j) {
            int h = hbase + j;
            float acc = 0.0f;
            #pragma unroll
            for (int s = 0; s < S_IN; ++s) acc = fmaf_(xv[s], W1[h * S_IN + s], acc);
            cur1[j] = acc + b1[h];
        }
    }

    float m1[UPW], m2[UPW];
    #pragma unroll
    for (int j = 0; j < UPW; ++j) { m1[j] = 0.0f; m2[j] = 0.0f; }

    __syncthreads();                            // staging done

    // ---- prologue: layer-1 at t=0 ----
    {
        unsigned int s1loc = 0u;
        #pragma unroll
        for (int j = 0; j < UPW; ++j) {
            float m = 0.95f * m1[j];
            m = m + cur1[j];
            bool sp = m > 1.0f;
            m1[j] = sp ? (m - 1.0f) : m;
            s1loc |= (sp ? 1u : 0u) << j;
        }
        s1buf[0][wq][lane] = s1loc;
    }
    __syncthreads();

    for (int t = 0; t < T_STEPS; ++t) {
        const int slot = t & 1;

        // ---- layer 2: full s1 mask (two u32 halves), exact ascending-k chain ----
        unsigned int p0 = s1buf[slot][0][lane], p1 = s1buf[slot][1][lane];
        unsigned int p2 = s1buf[slot][2][lane], p3 = s1buf[slot][3][lane];
        const unsigned int mlo = p0 | (p1 << 16);
        const unsigned int mhi = p2 | (p3 << 16);

        #pragma unroll
        for (int j = 0; j < UPW; ++j) m2[j] = 0.95f * m2[j];

        #pragma unroll 8
        for (int k = 0; k < 32; ++k) {
            const float sf = (float)((mlo >> k) & 1u);        // v_bfe + v_cvt
            const float4 w0 = *reinterpret_cast<const float4*>(&w2s[k][hbase]);
            const float4 w1 = *reinterpret_cast<const float4*>(&w2s[k][hbase + 4]);
            const float4 w2 = *reinterpret_cast<const float4*>(&w2s[k][hbase + 8]);
            const float4 w3 = *reinterpret_cast<const float4*>(&w2s[k][hbase + 12]);
            m2[ 0] = fmaf_(sf, w0.x, m2[ 0]);  m2[ 1] = fmaf_(sf, w0.y, m2[ 1]);
            m2[ 2] = fmaf_(sf, w0.z, m2[ 2]);  m2[ 3] = fmaf_(sf, w0.w, m2[ 3]);
            m2[ 4] = fmaf_(sf, w1.x, m2[ 4]);  m2[ 5] = fmaf_(sf, w1.y, m2[ 5]);
            m2[ 6] = fmaf_(sf, w1.z, m2[ 6]);  m2[ 7] = fmaf_(sf, w1.w, m2[ 7]);
            m2[ 8] = fmaf_(sf, w2.x, m2[ 8]);  m2[ 9] = fmaf_(sf, w2.y, m2[ 9]);
            m2[10] = fmaf_(sf, w2.z, m2[10]);  m2[11] = fmaf_(sf, w2.w, m2[11]);
            m2[12] = fmaf_(sf, w3.x, m2[12]);  m2[13] = fmaf_(sf, w3.y, m2[13]);
            m2[14] = fmaf_(sf, w3.z, m2[14]);  m2[15] = fmaf_(sf, w3.w, m2[15]);
        }
        #pragma unroll 8
        for (int k = 0; k < 32; ++k) {
            const float sf = (float)((mhi >> k) & 1u);
            const float4 w0 = *reinterpret_cast<const float4*>(&w2s[k + 32][hbase]);
            const float4 w1 = *reinterpret_cast<const float4*>(&w2s[k + 32][hbase + 4]);
            const float4 w2 = *reinterpret_cast<const float4*>(&w2s[k + 32][hbase + 8]);
            const float4 w3 = *reinterpret_cast<const float4*>(&w2s[k + 32][hbase + 12]);
            m2[ 0] = fmaf_(sf, w0.x, m2[ 0]);  m2[ 1] = fmaf_(sf, w0.y, m2[ 1]);
            m2[ 2] = fmaf_(sf, w0.z, m2[ 2]);  m2[ 3] = fmaf_(sf, w0.w, m2[ 3]);
            m2[ 4] = fmaf_(sf, w1.x, m2[ 4]);  m2[ 5] = fmaf_(sf, w1.y, m2[ 5]);
            m2[ 6] = fmaf_(sf, w1.z, m2[ 6]);  m2[ 7] = fmaf_(sf, w1.w, m2[ 7]);
            m2[ 8] = fmaf_(sf, w2.x, m2[ 8]);  m2[ 9] = fmaf_(sf, w2.y, m2[ 9]);
            m2[10] = fmaf_(sf, w2.z, m2[10]);  m2[11] = fmaf_(sf, w2.w, m2[11]);
            m2[12] = fmaf_(sf, w3.x, m2[12]);  m2[13] = fmaf_(sf, w3.y, m2[13]);
            m2[14] = fmaf_(sf, w3.z, m2[14]);  m2[15] = fmaf_(sf, w3.w, m2[15]);
        }

        // ---- layer-2 spikes + pre-counts (this wave's 16 units, all 64 elems) ----
        unsigned int s2loc = 0u;
        int myCnt = 0;
        #pragma unroll
        for (int j = 0; j < UPW; ++j) {
            float m = m2[j] + b2[hbase + j];
            bool sp = m > 1.0f;
            float s2f = sp ? 1.0f : 0.0f;
            m2[j] = m - s2f;
            s2loc |= (sp ? 1u : 0u) << j;
            int cnt = (int)__popcll(__ballot(sp));
            myCnt = (lane == j) ? cnt : myCnt;
        }
        s2buf[slot][wq][lane] = s2loc;
        if (lane < UPW) lds_pre[t * H + hbase + lane] = myCnt;  // single writer per h

        // ---- layer 1 for t+1 (independent of layer 3) ----
        if (t < T_STEPS - 1) {
            unsigned int s1loc = 0u;
            #pragma unroll
            for (int j = 0; j < UPW; ++j) {
                float m = 0.95f * m1[j];
                m = m + cur1[j];
                bool sp = m > 1.0f;
                m1[j] = sp ? (m - 1.0f) : m;
                s1loc |= (sp ? 1u : 0u) << j;
            }
            s1buf[slot ^ 1][wq][lane] = s1loc;
        }
        __syncthreads();

        // ---- layer 3: rotating duty wave, lane = block element, exact h-chain ----
        if (wq == (t & 3)) {
            unsigned int q0 = s2buf[slot][0][lane], q1 = s2buf[slot][1][lane];
            unsigned int q2 = s2buf[slot][2][lane], q3 = s2buf[slot][3][lane];
            ull s2v = (ull)(q0 | (q1 << 16)) | ((ull)(q2 | (q3 << 16)) << 32);
            float m3[A_OUT], ac[A_OUT];
            #pragma unroll
            for (int a = 0; a < A_OUT; ++a) { m3[a] = 0.95f * m3acc[lane][a]; ac[a] = m3acc[lane][4 + a]; }
            for (int h = 0; h < H; ++h) {        // h ascending: exact chain order
                float s2f = (float)((unsigned)s2v & 1u);
                s2v >>= 1;
                const float4 w = w3s[h];         // broadcast ds_read
                m3[0] = fmaf_(s2f, w.x, m3[0]);
                m3[1] = fmaf_(s2f, w.y, m3[1]);
                m3[2] = fmaf_(s2f, w.z, m3[2]);
                m3[3] = fmaf_(s2f, w.w, m3[3]);
            }
            int myPost = 0;
            #pragma unroll
            for (int a = 0; a < A_OUT; ++a) {
                float m = m3[a] + b3[a];
                bool sp = m > 1.0f;
                float s3f = sp ? 1.0f : 0.0f;
                m3[a] = m - s3f;
                ac[a] = ac[a] + s3f;
                int c = (int)__popcll(__ballot(sp));
                myPost = (lane == a) ? c : myPost;
            }
            if (lane < A_OUT) lds_post[t * A_OUT + lane] = myPost;
            if (t == T_STEPS - 1) {
                float r0 = ac[0] * 0.0625f, r1 = ac[1] * 0.0625f;
                float r2 = ac[2] * 0.0625f, r3 = ac[3] * 0.0625f;
                float mx = fmaxf(fmaxf(r0, r1), fmaxf(r2, r3));
                float e0 = expf(r0 - mx), e1 = expf(r1 - mx);
                float e2 = expf(r2 - mx), e3 = expf(r3 - mx);
                float s = ((e0 + e1) + e2) + e3;
                reinterpret_cast<float4*>(out)[blockIdx.x * EPB + lane] =
                    make_float4(e0 / s, e1 / s, e2 / s, e3 / s);
            } else {
                #pragma unroll
                for (int a = 0; a < A_OUT; ++a) { m3acc[lane][a] = m3[a]; m3acc[lane][4 + a] = ac[a]; }
            }
        }
    }

    __syncthreads();
    for (int i = tid; i < T_STEPS * H; i += 256) atomicAdd(&g_pre[i], lds_pre[i]);
    if (tid < T_STEPS * A_OUT) atomicAdd(&g_post[tid], lds_post[tid]);
}

// elig_t = 0.95*elig_{t-1} + (A_PLUS-A_MINUS) * outer(post_t, pre_t); exact counts/B.
__global__ void snn_elig(const int* __restrict__ g_pre, const int* __restrict__ g_post,
                         const float* __restrict__ elig0, float* __restrict__ out) {
#pragma clang fp contract(off)
    int i = threadIdx.x;                 // 256 = A_OUT * H
    int a = i >> 6, h = i & 63;
    float e = elig0[i];
    const float invB = 1.0f / 65536.0f;
    for (int t = 0; t < T_STEPS; ++t) {
        float pre  = (float)g_pre[t * H + h] * invB;
        float post = (float)g_post[t * A_OUT + a] * invB;
        e = 0.95f * e + (-0.002f) * (post * pre);
    }
    out[NB * A_OUT + i] = e;
}

extern "C" void kernel_launch(void* const* d_in, const int* in_sizes, int n_in,
                              void* d_out, int out_size, void* d_ws, size_t ws_size,
                              hipStream_t stream) {
    const float* x     = (const float*)d_in[0];
    const float* W1    = (const float*)d_in[1];
    const float* b1    = (const float*)d_in[2];
    const float* W2    = (const float*)d_in[3];
    const float* b2    = (const float*)d_in[4];
    const float* W3    = (const float*)d_in[5];
    const float* b3    = (const float*)d_in[6];
    const float* elig0 = (const float*)d_in[7];
    float* out = (float*)d_out;

    char* ws = (char*)d_ws;
    int*   g_pre  = (int*)(ws);                    // 1024 ints
    int*   g_post = (int*)(ws + 4096);             // 64 ints
    float* W2T    = (float*)(ws + 8192);           // 4096 floats
    float* W3T    = (float*)(ws + 8192 + 16384);   // 256 floats

    (void)hipMemsetAsync(ws, 0, 4096 + 256, stream);  // zero count accumulators every launch
    snn_prep<<<17, 256, 0, stream>>>(W2, W3, W2T, W3T);
    snn_main<<<NB / EPB, 256, 0, stream>>>(x, W1, b1, W2T, b2, W3T, b3, out, g_pre, g_post);
    snn_elig<<<1, 256, 0, stream>>>(g_pre, g_post, elig0, out);
}

// Round 14
// 171.523 us; speedup vs baseline: 1.3421x; 1.3421x over previous
//
#include <hip/hip_runtime.h>

#define T_STEPS 16
#define H 64
#define S_IN 25
#define A_OUT 4
#define NB 65536
#define UPW 8             // units per thread (H / 8 waves)
#define WPB 8             // waves per block
#define EPB 128           // batch elements per block (two per lane)

typedef unsigned long long ull;

__device__ __forceinline__ float fmaf_(float a, float b, float c) { return __builtin_fmaf(a, b, c); }

// Transpose W2 (64x64) and W3 (4x64) into workspace (row-major [k][h], [h][a]).
__global__ void snn_prep(const float* __restrict__ W2, const float* __restrict__ W3,
                         float* __restrict__ W2T, float* __restrict__ W3T) {
    int i = blockIdx.x * blockDim.x + threadIdx.x;
    if (i < H * H) { int h = i >> 6, k = i & 63; W2T[k * H + h] = W2[h * H + k]; }
    if (i < A_OUT * H) { int a = i >> 6, h = i & 63; W3T[h * A_OUT + a] = W3[a * H + h]; }
}

// R8 structure + 2 batch elements per thread: each wave-uniform s_load_dwordx8
// now feeds 16 FMAs (was 8) -> per-FMA wait frequency halves, per-CU s_load
// traffic halves. Weights stay on the scalar path (R7/R11/R13: any VGPR-side
// weight buffering spills or floods VMEM). launch_bounds(512,4) -> 128-VGPR
// cap fits 2x state (48f) + pipeline without spilling.
__global__ __launch_bounds__(512, 4) void snn_main(
    const float* __restrict__ x,
    const float* __restrict__ W1, const float* __restrict__ b1,
    const float* __restrict__ W2T, const float* __restrict__ b2,
    const float* __restrict__ W3T, const float* __restrict__ b3,
    float* __restrict__ out, int* __restrict__ g_pre, int* __restrict__ g_post)
{
#pragma clang fp contract(off)
    __shared__ float4 w3s[H];                   // 1 KB: W3T rows, broadcast-read
    __shared__ unsigned int s1buf[2][WPB][EPB]; // [slot][wave][elem] 8-bit masks
    __shared__ unsigned int s2buf[2][WPB][EPB];
    __shared__ float m3acc[EPB][8];             // [elem][0..3]=m3, [4..7]=acc
    __shared__ int lds_pre[T_STEPS * H];
    __shared__ int lds_post[T_STEPS * A_OUT];

    const int tid = threadIdx.x;
    if (tid < H) w3s[tid] = reinterpret_cast<const float4*>(W3T)[tid];
    for (int i = tid; i < T_STEPS * H; i += 512) lds_pre[i] = 0;
    if (tid < T_STEPS * A_OUT) lds_post[tid] = 0;
    for (int i = tid; i < EPB * 8; i += 512) (&m3acc[0][0])[i] = 0.0f;   // strided (R12 lesson)

    const int lane  = tid & 63;
    const int wq    = __builtin_amdgcn_readfirstlane(tid >> 6);  // wave 0..7 (SGPR)
    const int hbase = UPW * wq;                                  // this wave's unit range
    const int bA    = blockIdx.x * EPB + lane;                   // element A
    const int bB    = bA + 64;                                   // element B

    // cur1 for both elements' 8 units (exact s-chain), one element at a time
    // to keep xv[25] register pressure bounded.
    float cur1A[UPW], cur1B[UPW];
    {
        float xv[S_IN];
        #pragma unroll
        for (int s = 0; s < S_IN; ++s) xv[s] = x[bA * S_IN + s];
        #pragma unroll
        for (int j = 0; j < UPW; ++j) {
            int h = hbase + j;
            float acc = 0.0f;
            #pragma unroll
            for (int s = 0; s < S_IN; ++s) acc = fmaf_(xv[s], W1[h * S_IN + s], acc);
            cur1A[j] = acc + b1[h];
        }
        #pragma unroll
        for (int s = 0; s < S_IN; ++s) xv[s] = x[bB * S_IN + s];
        #pragma unroll
        for (int j = 0; j < UPW; ++j) {
            int h = hbase + j;
            float acc = 0.0f;
            #pragma unroll
            for (int s = 0; s < S_IN; ++s) acc = fmaf_(xv[s], W1[h * S_IN + s], acc);
            cur1B[j] = acc + b1[h];
        }
    }

    float m1A[UPW], m1B[UPW], m2A[UPW], m2B[UPW];
    #pragma unroll
    for (int j = 0; j < UPW; ++j) { m1A[j] = 0.0f; m1B[j] = 0.0f; m2A[j] = 0.0f; m2B[j] = 0.0f; }

    __syncthreads();                            // staging + init done

    // ---- prologue: layer-1 at t=0 for both elements ----
    {
        unsigned int sA = 0u, sB = 0u;
        #pragma unroll
        for (int j = 0; j < UPW; ++j) {
            float ma = 0.95f * m1A[j]; ma = ma + cur1A[j];
            bool pa = ma > 1.0f; m1A[j] = pa ? (ma - 1.0f) : ma; sA |= (pa ? 1u : 0u) << j;
            float mb = 0.95f * m1B[j]; mb = mb + cur1B[j];
            bool pb = mb > 1.0f; m1B[j] = pb ? (mb - 1.0f) : mb; sB |= (pb ? 1u : 0u) << j;
        }
        s1buf[0][wq][lane] = sA;
        s1buf[0][wq][lane + 64] = sB;
    }
    __syncthreads();

    for (int t = 0; t < T_STEPS; ++t) {
        const int slot = t & 1;

        // ---- assemble full 64-bit s1 masks (two u32 words) per element ----
        unsigned int mloA, mhiA, mloB, mhiB;
        {
            unsigned int a0 = s1buf[slot][0][lane], a1 = s1buf[slot][1][lane];
            unsigned int a2 = s1buf[slot][2][lane], a3 = s1buf[slot][3][lane];
            unsigned int a4 = s1buf[slot][4][lane], a5 = s1buf[slot][5][lane];
            unsigned int a6 = s1buf[slot][6][lane], a7 = s1buf[slot][7][lane];
            mloA = a0 | (a1 << 8) | (a2 << 16) | (a3 << 24);
            mhiA = a4 | (a5 << 8) | (a6 << 16) | (a7 << 24);
            unsigned int c0 = s1buf[slot][0][lane + 64], c1 = s1buf[slot][1][lane + 64];
            unsigned int c2 = s1buf[slot][2][lane + 64], c3 = s1buf[slot][3][lane + 64];
            unsigned int c4 = s1buf[slot][4][lane + 64], c5 = s1buf[slot][5][lane + 64];
            unsigned int c6 = s1buf[slot][6][lane + 64], c7 = s1buf[slot][7][lane + 64];
            mloB = c0 | (c1 << 8) | (c2 << 16) | (c3 << 24);
            mhiB = c4 | (c5 << 8) | (c6 << 16) | (c7 << 24);
        }

        #pragma unroll
        for (int j = 0; j < UPW; ++j) { m2A[j] = 0.95f * m2A[j]; m2B[j] = 0.95f * m2B[j]; }

        // exact ascending-k chain; one uniform s_load row feeds 16 FMAs
        #pragma unroll 8
        for (int k = 0; k < 32; ++k) {
            const float sfA = (float)((mloA >> k) & 1u);
            const float sfB = (float)((mloB >> k) & 1u);
            const float* wr = W2T + k * H + hbase;
            #pragma unroll
            for (int j = 0; j < UPW; ++j) {
                const float w = wr[j];
                m2A[j] = fmaf_(sfA, w, m2A[j]);
                m2B[j] = fmaf_(sfB, w, m2B[j]);
            }
        }
        #pragma unroll 8
        for (int k = 0; k < 32; ++k) {
            const float sfA = (float)((mhiA >> k) & 1u);
            const float sfB = (float)((mhiB >> k) & 1u);
            const float* wr = W2T + (k + 32) * H + hbase;
            #pragma unroll
            for (int j = 0; j < UPW; ++j) {
                const float w = wr[j];
                m2A[j] = fmaf_(sfA, w, m2A[j]);
                m2B[j] = fmaf_(sfB, w, m2B[j]);
            }
        }

        // ---- layer-2 spikes + pre-counts (8 units x 128 elems via 2 ballots) ----
        unsigned int s2A = 0u, s2B = 0u;
        int myCnt = 0;
        #pragma unroll
        for (int j = 0; j < UPW; ++j) {
            float ma = m2A[j] + b2[hbase + j];
            bool pa = ma > 1.0f;
            m2A[j] = ma - (pa ? 1.0f : 0.0f);
            s2A |= (pa ? 1u : 0u) << j;
            float mb = m2B[j] + b2[hbase + j];
            bool pb = mb > 1.0f;
            m2B[j] = mb - (pb ? 1.0f : 0.0f);
            s2B |= (pb ? 1u : 0u) << j;
            int cnt = (int)__popcll(__ballot(pa)) + (int)__popcll(__ballot(pb));
            myCnt = (lane == j) ? cnt : myCnt;
        }
        s2buf[slot][wq][lane] = s2A;
        s2buf[slot][wq][lane + 64] = s2B;
        if (lane < UPW) lds_pre[t * H + hbase + lane] = myCnt;   // single writer per (t,h)

        // ---- layer 1 for t+1 (both elements) ----
        if (t < T_STEPS - 1) {
            unsigned int sA = 0u, sB = 0u;
            #pragma unroll
            for (int j = 0; j < UPW; ++j) {
                float ma = 0.95f * m1A[j]; ma = ma + cur1A[j];
                bool pa = ma > 1.0f; m1A[j] = pa ? (ma - 1.0f) : ma; sA |= (pa ? 1u : 0u) << j;
                float mb = 0.95f * m1B[j]; mb = mb + cur1B[j];
                bool pb = mb > 1.0f; m1B[j] = pb ? (mb - 1.0f) : mb; sB |= (pb ? 1u : 0u) << j;
            }
            s1buf[slot ^ 1][wq][lane] = sA;
            s1buf[slot ^ 1][wq][lane + 64] = sB;
        }
        __syncthreads();

        // ---- layer 3: two rotating duty waves, 64 elems each, exact h-chain ----
        const int duty = wq & 3;
        if (duty == (t & 3)) {
            const int el = (wq < 4) ? lane : (lane + 64);        // elem handled by this lane
            unsigned int q0 = s2buf[slot][0][el], q1 = s2buf[slot][1][el];
            unsigned int q2 = s2buf[slot][2][el], q3 = s2buf[slot][3][el];
            unsigned int q4 = s2buf[slot][4][el], q5 = s2buf[slot][5][el];
            unsigned int q6 = s2buf[slot][6][el], q7 = s2buf[slot][7][el];
            ull s2v = (ull)(q0 | (q1 << 8) | (q2 << 16) | (q3 << 24))
                    | ((ull)(q4 | (q5 << 8) | (q6 << 16) | (q7 << 24)) << 32);
            float m3[A_OUT], ac[A_OUT];
            #pragma unroll
            for (int a = 0; a < A_OUT; ++a) { m3[a] = 0.95f * m3acc[el][a]; ac[a] = m3acc[el][4 + a]; }
            for (int h = 0; h < H; ++h) {        // h ascending: exact chain order
                float s2f = (float)((unsigned)s2v & 1u);
                s2v >>= 1;
                const float4 w = w3s[h];         // broadcast ds_read
                m3[0] = fmaf_(s2f, w.x, m3[0]);
                m3[1] = fmaf_(s2f, w.y, m3[1]);
                m3[2] = fmaf_(s2f, w.z, m3[2]);
                m3[3] = fmaf_(s2f, w.w, m3[3]);
            }
            int myPost = 0;
            #pragma unroll
            for (int a = 0; a < A_OUT; ++a) {
                float m = m3[a] + b3[a];
                bool sp = m > 1.0f;
                float s3f = sp ? 1.0f : 0.0f;
                m3[a] = m - s3f;
                ac[a] = ac[a] + s3f;
                int c = (int)__popcll(__ballot(sp));
                myPost = (lane == a) ? c : myPost;
            }
            if (lane < A_OUT) atomicAdd(&lds_post[t * A_OUT + lane], myPost);  // 2 duty waves
            if (t == T_STEPS - 1) {
                float r0 = ac[0] * 0.0625f, r1 = ac[1] * 0.0625f;
                float r2 = ac[2] * 0.0625f, r3 = ac[3] * 0.0625f;
                float mx = fmaxf(fmaxf(r0, r1), fmaxf(r2, r3));
                float e0 = expf(r0 - mx), e1 = expf(r1 - mx);
                float e2 = expf(r2 - mx), e3 = expf(r3 - mx);
                float s = ((e0 + e1) + e2) + e3;
                reinterpret_cast<float4*>(out)[blockIdx.x * EPB + el] =
                    make_float4(e0 / s, e1 / s, e2 / s, e3 / s);
            } else {
                #pragma unroll
                for (int a = 0; a < A_OUT; ++a) { m3acc[el][a] = m3[a]; m3acc[el][4 + a] = ac[a]; }
            }
        }
    }

    __syncthreads();
    for (int i = tid; i < T_STEPS * H; i += 512) atomicAdd(&g_pre[i], lds_pre[i]);
    if (tid < T_STEPS * A_OUT) atomicAdd(&g_post[tid], lds_post[tid]);
}

// elig_t = 0.95*elig_{t-1} + (A_PLUS-A_MINUS) * outer(post_t, pre_t); exact counts/B.
__global__ void snn_elig(const int* __restrict__ g_pre, const int* __restrict__ g_post,
                         const float* __restrict__ elig0, float* __restrict__ out) {
#pragma clang fp contract(off)
    int i = threadIdx.x;                 // 256 = A_OUT * H
    int a = i >> 6, h = i & 63;
    float e = elig0[i];
    const float invB = 1.0f / 65536.0f;
    for (int t = 0; t < T_STEPS; ++t) {
        float pre  = (float)g_pre[t * H + h] * invB;
        float post = (float)g_post[t * A_OUT + a] * invB;
        e = 0.95f * e + (-0.002f) * (post * pre);
    }
    out[NB * A_OUT + i] = e;
}

extern "C" void kernel_launch(void* const* d_in, const int* in_sizes, int n_in,
                              void* d_out, int out_size, void* d_ws, size_t ws_size,
                              hipStream_t stream) {
    const float* x     = (const float*)d_in[0];
    const float* W1    = (const float*)d_in[1];
    const float* b1    = (const float*)d_in[2];
    const float* W2    = (const float*)d_in[3];
    const float* b2    = (const float*)d_in[4];
    const float* W3    = (const float*)d_in[5];
    const float* b3    = (const float*)d_in[6];
    const float* elig0 = (const float*)d_in[7];
    float* out = (float*)d_out;

    char* ws = (char*)d_ws;
    int*   g_pre  = (int*)(ws);                    // 1024 ints
    int*   g_post = (int*)(ws + 4096);             // 64 ints
    float* W2T    = (float*)(ws + 8192);           // 4096 floats
    float* W3T    = (float*)(ws + 8192 + 16384);   // 256 floats

    (void)hipMemsetAsync(ws, 0, 4096 + 256, stream);  // zero count accumulators every launch
    snn_prep<<<17, 256, 0, stream>>>(W2, W3, W2T, W3T);
    snn_main<<<NB / EPB, 512, 0, stream>>>(x, W1, b1, W2T, b2, W3T, b3, out, g_pre, g_post);
    snn_elig<<<1, 256, 0, stream>>>(g_pre, g_post, elig0, out);
}

// Round 15
// 156.033 us; speedup vs baseline: 1.4753x; 1.0993x over previous
//
#include <hip/hip_runtime.h>

#define T_STEPS 16
#define H 64
#define S_IN 25
#define A_OUT 4
#define NB 65536
#define UPW 8             // units per thread (H / 8 waves)
#define WPB 8             // waves per block
#define EPB 128           // batch elements per block (two per lane)

typedef unsigned long long ull;

__device__ __forceinline__ float fmaf_(float a, float b, float c) { return __builtin_fmaf(a, b, c); }

// Transpose W2 (64x64) and W3 (4x64) into workspace (row-major [k][h], [h][a]).
__global__ void snn_prep(const float* __restrict__ W2, const float* __restrict__ W3,
                         float* __restrict__ W2T, float* __restrict__ W3T) {
    int i = blockIdx.x * blockDim.x + threadIdx.x;
    if (i < H * H) { int h = i >> 6, k = i & 63; W2T[k * H + h] = W2[h * H + k]; }
    if (i < A_OUT * H) { int a = i >> 6, h = i & 63; W3T[h * A_OUT + a] = W3[a * H + h]; }
}

// R14 (E=2, s_load weights) + f32 spike exchange: layer-1 spikes stored as
// 0.0/1.0 floats in a single-buffer LDS tile; layer-2's per-k select is one
// ds_read_b32 per element (LDS pipe) instead of bfe+cvt (VALU) + mask
// assembly. Single buffer -> 2 barriers/t; LDS 49 KB -> 2 blocks/CU (same).
// waves_per_eu(4,4) pins the allocator to the true 128-VGPR budget (R14
// self-capped to 64 and spilled ~9 MB).
__global__ __launch_bounds__(512, 4) __attribute__((amdgpu_waves_per_eu(4, 4)))
void snn_main(
    const float* __restrict__ x,
    const float* __restrict__ W1, const float* __restrict__ b1,
    const float* __restrict__ W2T, const float* __restrict__ b2,
    const float* __restrict__ W3T, const float* __restrict__ b3,
    float* __restrict__ out, int* __restrict__ g_pre, int* __restrict__ g_post)
{
#pragma clang fp contract(off)
    __shared__ float s1f[H][EPB];               // 32 KB: s1 spikes as 0.0/1.0 (single buffer)
    __shared__ float4 w3s[H];                   // 1 KB: W3T rows, broadcast-read
    __shared__ unsigned int s2buf[2][WPB][EPB]; // 4 KB: s2 bit-masks (double-buffered)
    __shared__ float m3acc[EPB][8];             // 4 KB: [elem][0..3]=m3, [4..7]=acc
    __shared__ int lds_pre[T_STEPS * H];        // 4 KB
    __shared__ int lds_post[T_STEPS * A_OUT];   // 256 B

    const int tid = threadIdx.x;
    if (tid < H) w3s[tid] = reinterpret_cast<const float4*>(W3T)[tid];
    for (int i = tid; i < T_STEPS * H; i += 512) lds_pre[i] = 0;
    if (tid < T_STEPS * A_OUT) lds_post[tid] = 0;
    for (int i = tid; i < EPB * 8; i += 512) (&m3acc[0][0])[i] = 0.0f;   // strided (R12 lesson)

    const int lane  = tid & 63;
    const int wq    = __builtin_amdgcn_readfirstlane(tid >> 6);  // wave 0..7 (SGPR)
    const int hbase = UPW * wq;                                  // this wave's unit range
    const int bA    = blockIdx.x * EPB + lane;                   // element A
    const int bB    = bA + 64;                                   // element B

    // cur1 for both elements' 8 units (exact s-chain), one element at a time.
    float cur1A[UPW], cur1B[UPW];
    {
        float xv[S_IN];
        #pragma unroll
        for (int s = 0; s < S_IN; ++s) xv[s] = x[bA * S_IN + s];
        #pragma unroll
        for (int j = 0; j < UPW; ++j) {
            int h = hbase + j;
            float acc = 0.0f;
            #pragma unroll
            for (int s = 0; s < S_IN; ++s) acc = fmaf_(xv[s], W1[h * S_IN + s], acc);
            cur1A[j] = acc + b1[h];
        }
        #pragma unroll
        for (int s = 0; s < S_IN; ++s) xv[s] = x[bB * S_IN + s];
        #pragma unroll
        for (int j = 0; j < UPW; ++j) {
            int h = hbase + j;
            float acc = 0.0f;
            #pragma unroll
            for (int s = 0; s < S_IN; ++s) acc = fmaf_(xv[s], W1[h * S_IN + s], acc);
            cur1B[j] = acc + b1[h];
        }
    }

    float m1A[UPW], m1B[UPW], m2A[UPW], m2B[UPW];
    #pragma unroll
    for (int j = 0; j < UPW; ++j) { m1A[j] = 0.0f; m1B[j] = 0.0f; m2A[j] = 0.0f; m2B[j] = 0.0f; }

    __syncthreads();                            // staging + init done

    // ---- prologue: layer-1 at t=0, spikes as floats straight to s1f ----
    #pragma unroll
    for (int j = 0; j < UPW; ++j) {
        float ma = 0.95f * m1A[j]; ma = ma + cur1A[j];
        bool pa = ma > 1.0f; m1A[j] = pa ? (ma - 1.0f) : ma;
        s1f[hbase + j][lane] = pa ? 1.0f : 0.0f;
        float mb = 0.95f * m1B[j]; mb = mb + cur1B[j];
        bool pb = mb > 1.0f; m1B[j] = pb ? (mb - 1.0f) : mb;
        s1f[hbase + j][lane + 64] = pb ? 1.0f : 0.0f;
    }
    __syncthreads();

    for (int t = 0; t < T_STEPS; ++t) {
        const int slot = t & 1;

        #pragma unroll
        for (int j = 0; j < UPW; ++j) { m2A[j] = 0.95f * m2A[j]; m2B[j] = 0.95f * m2B[j]; }

        // ---- layer 2: exact ascending-k chain; sf via ds_read_b32 (stride-1,
        //      2-way = free), weights via wave-uniform s_load; 16 FMA/k. ----
        #pragma unroll 8
        for (int k = 0; k < H; ++k) {
            const float sfA = s1f[k][lane];
            const float sfB = s1f[k][lane + 64];
            const float* wr = W2T + k * H + hbase;
            #pragma unroll
            for (int j = 0; j < UPW; ++j) {
                const float w = wr[j];
                m2A[j] = fmaf_(sfA, w, m2A[j]);
                m2B[j] = fmaf_(sfB, w, m2B[j]);
            }
        }

        // ---- layer-2 spikes + pre-counts (8 units x 128 elems via 2 ballots) ----
        unsigned int s2A = 0u, s2B = 0u;
        int myCnt = 0;
        #pragma unroll
        for (int j = 0; j < UPW; ++j) {
            float ma = m2A[j] + b2[hbase + j];
            bool pa = ma > 1.0f;
            m2A[j] = ma - (pa ? 1.0f : 0.0f);
            s2A |= (pa ? 1u : 0u) << j;
            float mb = m2B[j] + b2[hbase + j];
            bool pb = mb > 1.0f;
            m2B[j] = mb - (pb ? 1.0f : 0.0f);
            s2B |= (pb ? 1u : 0u) << j;
            int cnt = (int)__popcll(__ballot(pa)) + (int)__popcll(__ballot(pb));
            myCnt = (lane == j) ? cnt : myCnt;
        }
        s2buf[slot][wq][lane] = s2A;
        s2buf[slot][wq][lane + 64] = s2B;
        if (lane < UPW) lds_pre[t * H + hbase + lane] = myCnt;   // single writer per (t,h)

        __syncthreads();     // barrier 1: everyone done READING s1f(t)

        // ---- layer 1 for t+1: overwrite s1f (single buffer) ----
        if (t < T_STEPS - 1) {
            #pragma unroll
            for (int j = 0; j < UPW; ++j) {
                float ma = 0.95f * m1A[j]; ma = ma + cur1A[j];
                bool pa = ma > 1.0f; m1A[j] = pa ? (ma - 1.0f) : ma;
                s1f[hbase + j][lane] = pa ? 1.0f : 0.0f;
                float mb = 0.95f * m1B[j]; mb = mb + cur1B[j];
                bool pb = mb > 1.0f; m1B[j] = pb ? (mb - 1.0f) : mb;
                s1f[hbase + j][lane + 64] = pb ? 1.0f : 0.0f;
            }
        }
        __syncthreads();     // barrier 2: s1f(t+1) complete; s2buf(t) visible

        // ---- layer 3: two rotating duty waves (overlaps others' next L2) ----
        const int duty = wq & 3;
        if (duty == (t & 3)) {
            const int el = (wq < 4) ? lane : (lane + 64);        // elem handled by this lane
            unsigned int q0 = s2buf[slot][0][el], q1 = s2buf[slot][1][el];
            unsigned int q2 = s2buf[slot][2][el], q3 = s2buf[slot][3][el];
            unsigned int q4 = s2buf[slot][4][el], q5 = s2buf[slot][5][el];
            unsigned int q6 = s2buf[slot][6][el], q7 = s2buf[slot][7][el];
            ull s2v = (ull)(q0 | (q1 << 8) | (q2 << 16) | (q3 << 24))
                    | ((ull)(q4 | (q5 << 8) | (q6 << 16) | (q7 << 24)) << 32);
            float m3[A_OUT], ac[A_OUT];
            #pragma unroll
            for (int a = 0; a < A_OUT; ++a) { m3[a] = 0.95f * m3acc[el][a]; ac[a] = m3acc[el][4 + a]; }
            for (int h = 0; h < H; ++h) {        // h ascending: exact chain order
                float s2f = (float)((unsigned)s2v & 1u);
                s2v >>= 1;
                const float4 w = w3s[h];         // broadcast ds_read
                m3[0] = fmaf_(s2f, w.x, m3[0]);
                m3[1] = fmaf_(s2f, w.y, m3[1]);
                m3[2] = fmaf_(s2f, w.z, m3[2]);
                m3[3] = fmaf_(s2f, w.w, m3[3]);
            }
            int myPost = 0;
            #pragma unroll
            for (int a = 0; a < A_OUT; ++a) {
                float m = m3[a] + b3[a];
                bool sp = m > 1.0f;
                float s3f = sp ? 1.0f : 0.0f;
                m3[a] = m - s3f;
                ac[a] = ac[a] + s3f;
                int c = (int)__popcll(__ballot(sp));
                myPost = (lane == a) ? c : myPost;
            }
            if (lane < A_OUT) atomicAdd(&lds_post[t * A_OUT + lane], myPost);  // 2 duty waves
            if (t == T_STEPS - 1) {
                float r0 = ac[0] * 0.0625f, r1 = ac[1] * 0.0625f;
                float r2 = ac[2] * 0.0625f, r3 = ac[3] * 0.0625f;
                float mx = fmaxf(fmaxf(r0, r1), fmaxf(r2, r3));
                float e0 = expf(r0 - mx), e1 = expf(r1 - mx);
                float e2 = expf(r2 - mx), e3 = expf(r3 - mx);
                float s = ((e0 + e1) + e2) + e3;
                reinterpret_cast<float4*>(out)[blockIdx.x * EPB + el] =
                    make_float4(e0 / s, e1 / s, e2 / s, e3 / s);
            } else {
                #pragma unroll
                for (int a = 0; a < A_OUT; ++a) { m3acc[el][a] = m3[a]; m3acc[el][4 + a] = ac[a]; }
            }
        }
    }

    __syncthreads();
    for (int i = tid; i < T_STEPS * H; i += 512) atomicAdd(&g_pre[i], lds_pre[i]);
    if (tid < T_STEPS * A_OUT) atomicAdd(&g_post[tid], lds_post[tid]);
}

// elig_t = 0.95*elig_{t-1} + (A_PLUS-A_MINUS) * outer(post_t, pre_t); exact counts/B.
__global__ void snn_elig(const int* __restrict__ g_pre, const int* __restrict__ g_post,
                         const float* __restrict__ elig0, float* __restrict__ out) {
#pragma clang fp contract(off)
    int i = threadIdx.x;                 // 256 = A_OUT * H
    int a = i >> 6, h = i & 63;
    float e = elig0[i];
    const float invB = 1.0f / 65536.0f;
    for (int t = 0; t < T_STEPS; ++t) {
        float pre  = (float)g_pre[t * H + h] * invB;
        float post = (float)g_post[t * A_OUT + a] * invB;
        e = 0.95f * e + (-0.002f) * (post * pre);
    }
    out[NB * A_OUT + i] = e;
}

extern "C" void kernel_launch(void* const* d_in, const int* in_sizes, int n_in,
                              void* d_out, int out_size, void* d_ws, size_t ws_size,
                              hipStream_t stream) {
    const float* x     = (const float*)d_in[0];
    const float* W1    = (const float*)d_in[1];
    const float* b1    = (const float*)d_in[2];
    const float* W2    = (const float*)d_in[3];
    const float* b2    = (const float*)d_in[4];
    const float* W3    = (const float*)d_in[5];
    const float* b3    = (const float*)d_in[6];
    const float* elig0 = (const float*)d_in[7];
    float* out = (float*)d_out;

    char* ws = (char*)d_ws;
    int*   g_pre  = (int*)(ws);                    // 1024 ints
    int*   g_post = (int*)(ws + 4096);             // 64 ints
    float* W2T    = (float*)(ws + 8192);           // 4096 floats
    float* W3T    = (float*)(ws + 8192 + 16384);   // 256 floats

    (void)hipMemsetAsync(ws, 0, 4096 + 256, stream);  // zero count accumulators every launch
    snn_prep<<<17, 256, 0, stream>>>(W2, W3, W2T, W3T);
    snn_main<<<NB / EPB, 512, 0, stream>>>(x, W1, b1, W2T, b2, W3T, b3, out, g_pre, g_post);
    snn_elig<<<1, 256, 0, stream>>>(g_pre, g_post, elig0, out);
}